// Round 3
// baseline (411.088 us; speedup 1.0000x reference)
//
#include <hip/hip_runtime.h>
#include <math.h>

// Input [32, 3, 512, 512] f32 -> output [32, 27, 512, 512] f32.
// Plane = 512*512 = 262144 px. Each thread handles 8 consecutive pixels
// (2 x fx4) of one batch image; all 27 output channels.
#define PLANE   262144
#define P4      65536        // float4 groups per plane
#define P8      32768        // 8-pixel groups per plane (2^15)
#define BATCH   32

// Clang-native vector type: __builtin_nontemporal_store requires a real
// vector type, not HIP's HIP_vector_type class.
typedef float fx4 __attribute__((ext_vector_type(4)));

__global__ __launch_bounds__(256) void sclayer_58746562675072_kernel(
        const fx4* __restrict__ in, fx4* __restrict__ out) {
    const int idx = blockIdx.x * blockDim.x + threadIdx.x;   // [0, BATCH*P8)
    const int b = idx >> 15;             // P8 == 2^15
    const int p = (idx & (P8 - 1)) * 2;  // fx4 index within plane (even)

    const fx4* inb = in + (size_t)b * (3 * P4) + p;
    fx4 xa[3], xb[3];
    #pragma unroll
    for (int c = 0; c < 3; ++c) {
        xa[c] = inb[c * P4];
        xb[c] = inb[c * P4 + 1];
    }

    // base[c][k]: c = 0..2 raw, 3..5 cos, 6..8 sin; k = pixel 0..7.
    float base[9][8];
    #pragma unroll
    for (int c = 0; c < 3; ++c) {
        const float xs[8] = {xa[c].x, xa[c].y, xa[c].z, xa[c].w,
                             xb[c].x, xb[c].y, xb[c].z, xb[c].w};
        #pragma unroll
        for (int k = 0; k < 8; ++k) {
            float x = xs[k];
            float s, co;
            __sincosf(x, &s, &co);
            base[c    ][k] = x;
            base[c + 3][k] = co;
            base[c + 6][k] = s;
        }
    }

    fx4* outb = out + (size_t)b * (27 * P4) + p;

    // Channels 0..8: base values (non-temporal streaming stores).
    #pragma unroll
    for (int c = 0; c < 9; ++c) {
        fx4 v0, v1;
        v0.x = base[c][0]; v0.y = base[c][1]; v0.z = base[c][2]; v0.w = base[c][3];
        v1.x = base[c][4]; v1.y = base[c][5]; v1.z = base[c][6]; v1.w = base[c][7];
        __builtin_nontemporal_store(v0, &outb[c * P4]);
        __builtin_nontemporal_store(v1, &outb[c * P4 + 1]);
    }

    // Channels 9..26: 18 pairwise products, torch-loop order
    // (i in 0..8, j in range(i, 9, 3)).
    constexpr int II[18] = {0,0,0, 1,1,1, 2,2,2, 3,3, 4,4, 5,5, 6, 7, 8};
    constexpr int JJ[18] = {0,3,6, 1,4,7, 2,5,8, 3,6, 4,7, 5,8, 6, 7, 8};
    #pragma unroll
    for (int t = 0; t < 18; ++t) {
        fx4 v0, v1;
        v0.x = base[II[t]][0] * base[JJ[t]][0];
        v0.y = base[II[t]][1] * base[JJ[t]][1];
        v0.z = base[II[t]][2] * base[JJ[t]][2];
        v0.w = base[II[t]][3] * base[JJ[t]][3];
        v1.x = base[II[t]][4] * base[JJ[t]][4];
        v1.y = base[II[t]][5] * base[JJ[t]][5];
        v1.z = base[II[t]][6] * base[JJ[t]][6];
        v1.w = base[II[t]][7] * base[JJ[t]][7];
        __builtin_nontemporal_store(v0, &outb[(9 + t) * P4]);
        __builtin_nontemporal_store(v1, &outb[(9 + t) * P4 + 1]);
    }
}

extern "C" void kernel_launch(void* const* d_in, const int* in_sizes, int n_in,
                              void* d_out, int out_size, void* d_ws, size_t ws_size,
                              hipStream_t stream) {
    const fx4* in  = (const fx4*)d_in[0];
    fx4*       out = (fx4*)d_out;
    const int total_threads = BATCH * P8;        // 1,048,576
    const int block = 256;
    const int grid  = total_threads / block;     // 4096
    sclayer_58746562675072_kernel<<<grid, block, 0, stream>>>(in, out);
}

// Round 4
// 336.568 us; speedup vs baseline: 1.2214x; 1.2214x over previous
//
#include <hip/hip_runtime.h>
#include <math.h>

// Input [32, 3, 512, 512] f32 -> output [32, 27, 512, 512] f32.
// Channel-specialized blocks: each block produces ONE output channel over a
// quarter-plane chunk as a single sequential write stream (fill-like).
// Block ordering is channel-inner: consecutive blocks cover the same input
// chunk -> the 3 input sub-planes (768 KB) stay hot in L2/L3.
#define P4      65536        // fx4 groups per 512x512 plane
#define CHUNK4  16384        // fx4 groups per chunk (quarter plane, 256 KB)
#define NCH     27
#define BATCH   32

typedef float fx4 __attribute__((ext_vector_type(4)));

// f: 0 = identity, 1 = cos, 2 = sin  (wave-uniform selector)
__device__ __forceinline__ fx4 apply_f(int f, fx4 x) {
    if (f == 0) return x;
    fx4 r;
    if (f == 1) {
        r.x = __cosf(x.x); r.y = __cosf(x.y); r.z = __cosf(x.z); r.w = __cosf(x.w);
    } else {
        r.x = __sinf(x.x); r.y = __sinf(x.y); r.z = __sinf(x.z); r.w = __sinf(x.w);
    }
    return r;
}

__global__ __launch_bounds__(256) void sclayer_58746562675072_kernel(
        const fx4* __restrict__ in, fx4* __restrict__ out) {
    const int blk   = blockIdx.x;
    const int ch    = blk % NCH;       // output channel (wave-uniform)
    const int chunk = blk / NCH;       // 0..127: (batch, quarter)
    const int b     = chunk >> 2;
    const int q     = chunk & 3;
    const int base4 = q * CHUNK4;      // fx4 offset within plane

    // Decode channel -> (src0, f0) [, (src1, f1)] with
    // base c: src = c%3, f = c/3;  product t: pair (i, j=i+3*t') per torch order.
    int s0, f0, s1 = -1, f1 = 0;
    if (ch < 9) {
        s0 = ch % 3; f0 = ch / 3;
    } else {
        int t = ch - 9, i = 0;
        while (true) {
            int cnt = ((8 - i) / 3) + 1;      // pairs with this i: 3,3,3,2,2,2,1,1,1
            if (t < cnt) break;
            t -= cnt; ++i;
        }
        int j = i + 3 * t;
        s0 = i % 3; f0 = i / 3;
        s1 = j % 3; f1 = j / 3;
    }

    const fx4* inb  = in  + (size_t)b * (3 * P4) + base4;
    fx4*       outb = out + (size_t)b * (NCH * P4) + (size_t)ch * P4 + base4;
    const fx4* src0 = inb + s0 * P4;
    const fx4* src1 = inb + (s1 < 0 ? s0 : s1) * P4;   // valid ptr either way
    const bool prod = (s1 >= 0);

    #pragma unroll 4
    for (int i = threadIdx.x; i < CHUNK4; i += 256) {
        fx4 v = apply_f(f0, src0[i]);
        if (prod) {
            fx4 w = apply_f(f1, src1[i]);
            v.x *= w.x; v.y *= w.y; v.z *= w.z; v.w *= w.w;
        }
        outb[i] = v;
    }
}

extern "C" void kernel_launch(void* const* d_in, const int* in_sizes, int n_in,
                              void* d_out, int out_size, void* d_ws, size_t ws_size,
                              hipStream_t stream) {
    const fx4* in  = (const fx4*)d_in[0];
    fx4*       out = (fx4*)d_out;
    const int grid = BATCH * 4 * NCH;     // 128 chunks x 27 channels = 3456 blocks
    sclayer_58746562675072_kernel<<<grid, 256, 0, stream>>>(in, out);
}

// Round 5
// 201.008 us; speedup vs baseline: 2.0451x; 1.6744x over previous
//
#include <hip/hip_runtime.h>
#include <math.h>

// Input [32, 3, 512, 512] f32 -> output [32, 27, 512, 512] f32.
// Lane-major mapping: each WAVE owns 128 consecutive fx4 (2 KB) of a plane;
// lane i handles fx4 indices {wave_base + i, wave_base + 64 + i}. Every store
// instruction is a dense 1 KB wave-burst, and each channel stream gets 2 KB
// contiguous per wave before hopping to the next 256 KB-strided channel.
#define P4      65536        // fx4 groups per 512x512 plane
#define WPP     512          // waves per plane (P4 / 128)
#define NCH     27
#define BATCH   32

typedef float fx4 __attribute__((ext_vector_type(4)));

__global__ __launch_bounds__(256) void sclayer_58746562675072_kernel(
        const fx4* __restrict__ in, fx4* __restrict__ out) {
    const int tid  = blockIdx.x * blockDim.x + threadIdx.x;
    const int wave = tid >> 6;           // global wave id
    const int lane = tid & 63;
    const int b    = wave >> 9;          // wave / WPP
    const int wip  = wave & (WPP - 1);   // wave within plane
    const int p0   = wip * 128 + lane;   // fx4 index, group 0 (group 1 at +64)

    const fx4* inb = in + (size_t)b * (3 * P4) + p0;
    fx4 x[3][2];
    #pragma unroll
    for (int c = 0; c < 3; ++c) {
        x[c][0] = inb[c * P4];
        x[c][1] = inb[c * P4 + 64];
    }

    // base[c][k]: c = 0..2 raw, 3..5 cos, 6..8 sin; k = g*4 + elem, g = 0..1.
    float base[9][8];
    #pragma unroll
    for (int c = 0; c < 3; ++c) {
        #pragma unroll
        for (int g = 0; g < 2; ++g) {
            const float xs[4] = {x[c][g].x, x[c][g].y, x[c][g].z, x[c][g].w};
            #pragma unroll
            for (int e = 0; e < 4; ++e) {
                float v = xs[e];
                float s, co;
                __sincosf(v, &s, &co);
                base[c    ][g * 4 + e] = v;
                base[c + 3][g * 4 + e] = co;
                base[c + 6][g * 4 + e] = s;
            }
        }
    }

    fx4* outb = out + (size_t)b * (NCH * P4) + p0;

    // Channels 0..8: base values. Two dense 1 KB wave-bursts per channel.
    #pragma unroll
    for (int c = 0; c < 9; ++c) {
        fx4 v0, v1;
        v0.x = base[c][0]; v0.y = base[c][1]; v0.z = base[c][2]; v0.w = base[c][3];
        v1.x = base[c][4]; v1.y = base[c][5]; v1.z = base[c][6]; v1.w = base[c][7];
        outb[c * P4]      = v0;
        outb[c * P4 + 64] = v1;
    }

    // Channels 9..26: 18 pairwise products, torch-loop order
    // (i in 0..8, j in range(i, 9, 3)).
    constexpr int II[18] = {0,0,0, 1,1,1, 2,2,2, 3,3, 4,4, 5,5, 6, 7, 8};
    constexpr int JJ[18] = {0,3,6, 1,4,7, 2,5,8, 3,6, 4,7, 5,8, 6, 7, 8};
    #pragma unroll
    for (int t = 0; t < 18; ++t) {
        fx4 v0, v1;
        v0.x = base[II[t]][0] * base[JJ[t]][0];
        v0.y = base[II[t]][1] * base[JJ[t]][1];
        v0.z = base[II[t]][2] * base[JJ[t]][2];
        v0.w = base[II[t]][3] * base[JJ[t]][3];
        v1.x = base[II[t]][4] * base[JJ[t]][4];
        v1.y = base[II[t]][5] * base[JJ[t]][5];
        v1.z = base[II[t]][6] * base[JJ[t]][6];
        v1.w = base[II[t]][7] * base[JJ[t]][7];
        outb[(9 + t) * P4]      = v0;
        outb[(9 + t) * P4 + 64] = v1;
    }
}

extern "C" void kernel_launch(void* const* d_in, const int* in_sizes, int n_in,
                              void* d_out, int out_size, void* d_ws, size_t ws_size,
                              hipStream_t stream) {
    const fx4* in  = (const fx4*)d_in[0];
    fx4*       out = (fx4*)d_out;
    const int total_threads = BATCH * WPP * 64;  // 1,048,576
    const int block = 256;
    const int grid  = total_threads / block;     // 4096
    sclayer_58746562675072_kernel<<<grid, block, 0, stream>>>(in, out);
}